// Round 9
// baseline (2114.215 us; speedup 1.0000x reference)
//
#include <hip/hip_runtime.h>
#include <stdint.h>

// LSTM B=32,T=512,D=1024,H=1024. 2 groups x 16 batches; 128 blocks/group.
// Block = 512 thr (8 waves), owns 8 h-cols (32 gate cols); W slice as f16 MFMA
// B-frags in 128KB LDS. h exchange: stego-tagged 16B units in IF (low mantissa
// bit of each f16 = 2-bit step counter per dword). Round 9: drain hygiene --
// (1) outputs batched 4 steps in regs, flushed at the post-detection vmcnt==0
// slack point (in-order vmcnt retirement made owner waves' spin drains wait on
// their own HBM store acks every step); (2) probes issued AFTER x-MFMAs with
// s_sleep(2) on non-owner waves so the first flight samples IF after publish
// visibility (was: guaranteed-stale first probe -> +1 RTT round every step);
// (3) x(t+1) prefetch at loop top so its drain overlaps probe flight.

typedef _Float16 f16;
typedef __attribute__((ext_vector_type(8))) _Float16 f16x8;
typedef __attribute__((ext_vector_type(4))) float f32x4;
typedef __attribute__((ext_vector_type(4))) unsigned int u32x4;

#define NG 2
#define NW 8
#define HBYTES (2 * NG * 2048 * 16)  // 131072

__device__ __forceinline__ float sigm(float v){ return 1.f/(1.f+__expf(-v)); }
__device__ __forceinline__ float tanh_(float v){ return 2.f/(1.f+__expf(-2.f*v)) - 1.f; }

__device__ __forceinline__ u32x4 ld16_sc(const void* p) {
  u32x4 r;
  asm volatile("global_load_dwordx4 %0, %1, off sc0 sc1" : "=v"(r) : "v"(p));
  return r;
}
__device__ __forceinline__ void st2_sc(void* p, uint32_t v) {
  asm volatile("global_store_short %0, %1, off sc0 sc1" :: "v"(p), "v"(v) : "memory");
}

__global__ __launch_bounds__(512, 1) void lstm_kernel(
    const float* __restrict__ xin, const float* __restrict__ amask,
    const int* __restrict__ nzidx, const float* __restrict__ Wx,
    const float* __restrict__ Wh, const float* __restrict__ bx,
    const float* __restrict__ bh, float* __restrict__ out,
    uint32_t* __restrict__ ws)
{
  // frag f = side*64 + kf*2 + nt  (side: 0=x,1=h; kf 0..31; nt 0..1)
  __shared__ __align__(16) f16 Wl[128][64][8];         // 128 KB
  __shared__ __align__(16) float pl[2][NW][2][64][4];  // 32 KB (parity ping-pong)

  const int tid  = threadIdx.x;
  const int lane = tid & 63;
  const int wid  = tid >> 6;
  const int r    = blockIdx.x & 127;
  const int G    = blockIdx.x >> 7;
  const int hbase = r * 8;

  uint8_t* hb8 = (uint8_t*)ws;

  // ---- prologue: W slice -> LDS frags (round-3 proven, conflict-free) ----
  for (int f = wid; f < 128; f += NW) {
    const int side = f >> 6, kf = (f >> 1) & 31, nt = f & 1;
    const int c16 = lane & 15, kslot_ = lane >> 4;
    const int g = nt * 2 + (c16 >> 3);
    const int gcol = g * 1024 + hbase + (c16 & 7);
    const int k0 = kf * 32 + kslot_ * 8;
    const float* Wsrc = side ? Wh : Wx;
    f16x8 v;
#pragma unroll
    for (int e = 0; e < 8; ++e) v[e] = (f16)Wsrc[(size_t)(k0 + e) * 4096 + gcol];
    *(f16x8*)&Wl[f][lane][0] = v;
  }
  // owner state (tid<128): owner = (batch b, h-col hc)
  const int b  = tid >> 3;
  const int hc = tid & 7;
  const int b_glob = G * 16 + b;
  float bias[4] = {0.f, 0.f, 0.f, 0.f};
  float cval = 0.f, mv_cur = 0.f;
  int myidx = -1;
  if (tid < 128) {
#pragma unroll
    for (int g = 0; g < 4; ++g) {
      const int gcol = g * 1024 + hbase + hc;
      bias[g] = bx[gcol] + bh[gcol];
    }
    myidx = nzidx[b_glob];
    mv_cur = amask[(size_t)b_glob * 512];
  }
  // output reg-buffer (4 steps; static slots only -- rule #20)
  float hmb0=0.f,hmb1=0.f,hmb2=0.f,hmb3=0.f, cmb0=0.f,cmb1=0.f,cmb2=0.f,cmb3=0.f;
  // preload x(0) into regs
  const int bb = lane & 15, kslot = lane >> 4;
  f32x4 xf[4][2];
  {
    const size_t xrow = ((size_t)(G * 16 + bb) * 512) * 1024;
#pragma unroll
    for (int q = 0; q < 4; ++q) {
      const float* xs = xin + xrow + (wid * 4 + q) * 32 + kslot * 8;
      xf[q][0] = *(const f32x4*)xs;
      xf[q][1] = *(const f32x4*)(xs + 4);
    }
  }
  __syncthreads();

  bool gave_up = false;
#pragma unroll 1
  for (int t = 0; t < 512; ++t) {
    const int ppl = t & 1;
    // ---- convert x(t) regs -> f16 frags (drains x loads from prev step) ----
    f16x8 xa[4];
#pragma unroll
    for (int q = 0; q < 4; ++q) {
      f16x8 a;
#pragma unroll
      for (int i = 0; i < 4; ++i) { a[i] = (f16)xf[q][0][i]; a[i + 4] = (f16)xf[q][1][i]; }
      xa[q] = a;
    }
    // ---- x(t+1) prefetch at loop top (drain overlaps probe flight) ----
    if (t + 1 < 512) {
      const size_t xrow = ((size_t)(G * 16 + bb) * 512 + (size_t)(t + 1)) * 1024;
#pragma unroll
      for (int q = 0; q < 4; ++q) {
        const float* xs = xin + xrow + (wid * 4 + q) * 32 + kslot * 8;
        xf[q][0] = *(const f32x4*)xs;
        xf[q][1] = *(const f32x4*)(xs + 4);
      }
    }
    // ---- x-side MFMAs ----
    f32x4 acc0 = {0.f,0.f,0.f,0.f}, acc1 = {0.f,0.f,0.f,0.f};
#pragma unroll
    for (int q = 0; q < 4; ++q) {
      const int kf = wid * 4 + q;
      f16x8 b0 = *(const f16x8*)&Wl[kf * 2 + 0][lane][0];
      f16x8 b1 = *(const f16x8*)&Wl[kf * 2 + 1][lane][0];
      acc0 = __builtin_amdgcn_mfma_f32_16x16x32_f16(xa[q], b0, acc0, 0, 0, 0);
      acc1 = __builtin_amdgcn_mfma_f32_16x16x32_f16(xa[q], b1, acc1, 0, 0, 0);
    }
    __builtin_amdgcn_sched_barrier(0);  // pin MFMAs before probe issue
    if (t > 0) {
      // ---- probes issued post-compute, phase-aligned to publish visibility ----
      const uint8_t* hsrc = hb8 + ((size_t)((t & 1) * NG + G) << 15);
      const uint32_t tb = ((uint32_t)(t >> 1) + 1u) & 3u;
      const uint32_t pat = (tb & 1u) | (((tb >> 1) & 1u) << 16);
      size_t aoff[4];
      u32x4 hq[4];
      if (wid >= 2) __builtin_amdgcn_s_sleep(2);  // owners are naturally late
#pragma unroll
      for (int q = 0; q < 4; ++q) {
        const int rsrc = (wid * 4 + q) * 4 + kslot;   // producer rank of these 8 cols
        aoff[q] = (size_t)(rsrc * 16 + bb) << 4;
        hq[q] = ld16_sc(hsrc + aoff[q]);
      }
      // ---- spin: drain-check-reissue (always vmcnt(0) before use) ----
      if (!gave_up) {
        bool got = false;
        int spins = 0;
        for (;;) {
          asm volatile("s_waitcnt vmcnt(0)" ::: "memory");
          __builtin_amdgcn_sched_barrier(0);
          bool ok = true;
#pragma unroll
          for (int q = 0; q < 4; ++q)
#pragma unroll
            for (int j = 0; j < 4; ++j) ok &= ((hq[q][j] & 0x00010001u) == pat);
          if (__all((int)ok)) { got = true; break; }
          if (++spins > (1 << 14)) break;   // safety valve (terminates, latched)
#pragma unroll
          for (int q = 0; q < 4; ++q) hq[q] = ld16_sc(hsrc + aoff[q]);
        }
        if (!got) gave_up = true;
      } else {
        asm volatile("s_waitcnt vmcnt(0)" ::: "memory");
        __builtin_amdgcn_sched_barrier(0);
      }
      // ---- post-detection flush: vmcnt==0 slack point, once per 4 steps ----
      if (tid < 128 && (t & 3) == 0) {
        const size_t ob0 = ((size_t)b_glob * 512 + (size_t)(t - 4)) * 1024
                         + (size_t)(hbase + hc);
        out[ob0]                    = hmb0; out[ob0 + 16777216u]        = hmb0;
        out[ob0 + 33554432u]        = cmb0;
        out[ob0 + 1024]             = hmb1; out[ob0 + 1024 + 16777216u] = hmb1;
        out[ob0 + 1024 + 33554432u] = cmb1;
        out[ob0 + 2048]             = hmb2; out[ob0 + 2048 + 16777216u] = hmb2;
        out[ob0 + 2048 + 33554432u] = cmb2;
        out[ob0 + 3072]             = hmb3; out[ob0 + 3072 + 16777216u] = hmb3;
        out[ob0 + 3072 + 33554432u] = cmb3;
      }
      // ---- h-side MFMAs ----
#pragma unroll
      for (int q = 0; q < 4; ++q) {
        union { u32x4 u; f16x8 v; } cu; cu.u = hq[q];
        const int kf = wid * 4 + q;
        f16x8 b0 = *(const f16x8*)&Wl[64 + kf * 2 + 0][lane][0];
        f16x8 b1 = *(const f16x8*)&Wl[64 + kf * 2 + 1][lane][0];
        acc0 = __builtin_amdgcn_mfma_f32_16x16x32_f16(cu.v, b0, acc0, 0, 0, 0);
        acc1 = __builtin_amdgcn_mfma_f32_16x16x32_f16(cu.v, b1, acc1, 0, 0, 0);
      }
    }
    *(f32x4*)&pl[ppl][wid][0][lane][0] = acc0;
    *(f32x4*)&pl[ppl][wid][1][lane][0] = acc1;
    __syncthreads();  // the ONLY barrier: pl[ppl] ready; waves sprint to t+1
    // ---- owners: reduce, gates, state, publish, buffer outputs ----
    if (tid < 128) {
      float s[4];
#pragma unroll
      for (int g = 0; g < 4; ++g) {
        const int lp = ((g & 1) * 8 + hc) + 16 * (b >> 2);
        const int reg = b & 3;
        float v = bias[g];
#pragma unroll
        for (int w = 0; w < NW; ++w) v += pl[ppl][w][g >> 1][lp][reg];
        s[g] = v;
      }
      const float ig = sigm(s[0]);
      const float fg = sigm(s[1]);
      const float gg = tanh_(s[2]);
      const float og = sigm(s[3]);
      cval = fg * cval + ig * gg;
      const float hval = og * tanh_(cval);
      // publish FIRST: single 2B stego-tagged store, fire-and-forget
      if (t < 511) {
        union { f16 f; uint16_t u; } pk; pk.f = (f16)hval;
        const uint32_t tbp = ((uint32_t)((t + 1) >> 1) + 1u) & 3u;
        const uint32_t bitv = (hc & 1) ? ((tbp >> 1) & 1u) : (tbp & 1u);
        const uint32_t val = ((uint32_t)pk.u & 0xFFFEu) | bitv;
        uint8_t* dst = hb8 + ((size_t)(((t + 1) & 1) * NG + G) << 15)
                     + ((size_t)(r * 16 + b) << 4) + (hc << 1);
        st2_sc(dst, val);
      }
      // buffer outputs in static slots (flushed at post-detection points)
      const float hm = hval * mv_cur, cm = cval * mv_cur;
      const int sl = t & 3;
      if (sl == 0)      { hmb0 = hm; cmb0 = cm; }
      else if (sl == 1) { hmb1 = hm; cmb1 = cm; }
      else if (sl == 2) { hmb2 = hm; cmb2 = cm; }
      else              { hmb3 = hm; cmb3 = cm; }
      if (t == myidx)   // rare (once per thread per run): immediate store ok
        out[50331648u + (size_t)b_glob * 1024 + (size_t)(hbase + hc)] = hval;
      if (t + 1 < 512) mv_cur = amask[(size_t)b_glob * 512 + (size_t)(t + 1)];
    }
  }
  // ---- final flush: steps 508..511 ----
  if (tid < 128) {
    const size_t ob0 = ((size_t)b_glob * 512 + 508) * 1024 + (size_t)(hbase + hc);
    out[ob0]                    = hmb0; out[ob0 + 16777216u]        = hmb0;
    out[ob0 + 33554432u]        = cmb0;
    out[ob0 + 1024]             = hmb1; out[ob0 + 1024 + 16777216u] = hmb1;
    out[ob0 + 1024 + 33554432u] = cmb1;
    out[ob0 + 2048]             = hmb2; out[ob0 + 2048 + 16777216u] = hmb2;
    out[ob0 + 2048 + 33554432u] = cmb2;
    out[ob0 + 3072]             = hmb3; out[ob0 + 3072 + 16777216u] = hmb3;
    out[ob0 + 3072 + 33554432u] = cmb3;
  }
}

extern "C" void kernel_launch(void* const* d_in, const int* in_sizes, int n_in,
                              void* d_out, int out_size, void* d_ws, size_t ws_size,
                              hipStream_t stream) {
  const float* xin   = (const float*)d_in[0];
  const float* amask = (const float*)d_in[1];
  const int*   nzidx = (const int*)d_in[2];
  const float* Wx    = (const float*)d_in[3];
  const float* Wh    = (const float*)d_in[4];
  const float* bx    = (const float*)d_in[5];
  const float* bh    = (const float*)d_in[6];
  float* out = (float*)d_out;
  uint32_t* ws = (uint32_t*)d_ws;

  // zero the tagged h-buffer every launch (stale tags differ from fresh expectations)
  hipMemsetAsync(d_ws, 0, HBYTES, stream);

  void* args[] = {(void*)&xin, (void*)&amask, (void*)&nzidx, (void*)&Wx,
                  (void*)&Wh, (void*)&bx, (void*)&bh, (void*)&out, (void*)&ws};
  hipError_t e = hipLaunchCooperativeKernel((const void*)lstm_kernel, dim3(256), dim3(512),
                                            args, 0, stream);
  if (e != hipSuccess) {
    lstm_kernel<<<dim3(256), dim3(512), 0, stream>>>(xin, amask, nzidx, Wx, Wh, bx, bh, out, ws);
  }
}